// Round 8
// baseline (185.289 us; speedup 1.0000x reference)
//
#include <hip/hip_runtime.h>
#include <hip/hip_bf16.h>

#define NN 4096
#define IN_DIM 512
#define NH 8
#define DD 64
#define HD 512    // NH*DD
#define QCAP 128  // per-quarter cap: Binomial(1024,.05) mean 51 sigma 7 -> +11 sigma
#define RCAP 448  // per-row cap: mean 205 sigma 14 -> +17 sigma

// Workspace: d1b 4MB + src/trg 0.25MB ~= 4.4 MB (R3 lesson: stay small).

typedef __attribute__((ext_vector_type(8))) short short8;
typedef __attribute__((ext_vector_type(4))) float f32x4;

static __device__ __forceinline__ unsigned short f2bf(float x) {
    __hip_bfloat16 h = __float2bfloat16(x);
    return *reinterpret_cast<unsigned short*>(&h);
}

static __device__ __forceinline__ short8 cvt8(float4 a, float4 b) {
    short8 r;
    r[0] = (short)f2bf(a.x); r[1] = (short)f2bf(a.y);
    r[2] = (short)f2bf(a.z); r[3] = (short)f2bf(a.w);
    r[4] = (short)f2bf(b.x); r[5] = (short)f2bf(b.y);
    r[6] = (short)f2bf(b.z); r[7] = (short)f2bf(b.w);
    return r;
}

// ---------------- K1: fused cast + GEMM (bf16 MFMA) + src/trg projection -----
// 64n x 64m per WG; m-tile == one head h = blockIdx.x. fp32 fragments loaded
// straight from global (k-major), converted to bf16 in-register (RNE, same as
// the old k_cast2 path). C/D: col=lane&15, row=(lane>>4)*4+reg (m89-verified).
// Epilogue: bf16 V write + per-head src/trg reduction (fp32 accumulators,
// quad-local shfl_xor butterfly over the 16 col-lanes).
__global__ __launch_bounds__(256) void k_prep(const float* __restrict__ A,
                                              const float* __restrict__ W,
                                              const float* __restrict__ bias,
                                              const float* __restrict__ sp,
                                              const float* __restrict__ tp,
                                              unsigned short* __restrict__ Cb,
                                              float* __restrict__ src,
                                              float* __restrict__ trg) {
    const int lane = threadIdx.x & 63;
    const int w = threadIdx.x >> 6;
    const int col = lane & 15;
    const int quad = lane >> 4;
    const int koff = quad * 8;
    const int h = blockIdx.x;
    const int m0 = h * 64;
    const int n0 = blockIdx.y * 64;

    const float* apf  = A + (size_t)(n0 + w * 16 + col) * IN_DIM + koff;
    const float* bpf0 = W + (size_t)(m0 +  0 + col) * IN_DIM + koff;
    const float* bpf1 = W + (size_t)(m0 + 16 + col) * IN_DIM + koff;
    const float* bpf2 = W + (size_t)(m0 + 32 + col) * IN_DIM + koff;
    const float* bpf3 = W + (size_t)(m0 + 48 + col) * IN_DIM + koff;

    f32x4 acc0 = {0.f, 0.f, 0.f, 0.f}, acc1 = acc0, acc2 = acc0, acc3 = acc0;

#pragma unroll 4
    for (int ks = 0; ks < 16; ks++) {
        const int o = ks * 32;
        short8 a  = cvt8(*(const float4*)(apf  + o), *(const float4*)(apf  + o + 4));
        short8 b0 = cvt8(*(const float4*)(bpf0 + o), *(const float4*)(bpf0 + o + 4));
        short8 b1 = cvt8(*(const float4*)(bpf1 + o), *(const float4*)(bpf1 + o + 4));
        short8 b2 = cvt8(*(const float4*)(bpf2 + o), *(const float4*)(bpf2 + o + 4));
        short8 b3 = cvt8(*(const float4*)(bpf3 + o), *(const float4*)(bpf3 + o + 4));
        acc0 = __builtin_amdgcn_mfma_f32_16x16x32_bf16(a, b0, acc0, 0, 0, 0);
        acc1 = __builtin_amdgcn_mfma_f32_16x16x32_bf16(a, b1, acc1, 0, 0, 0);
        acc2 = __builtin_amdgcn_mfma_f32_16x16x32_bf16(a, b2, acc2, 0, 0, 0);
        acc3 = __builtin_amdgcn_mfma_f32_16x16x32_bf16(a, b3, acc3, 0, 0, 0);
    }

    const int rbase = n0 + w * 16 + quad * 4;
    f32x4 accs[4] = {acc0, acc1, acc2, acc3};
    float ps[4] = {0.f, 0.f, 0.f, 0.f};
    float pt[4] = {0.f, 0.f, 0.f, 0.f};
#pragma unroll
    for (int mt = 0; mt < 4; mt++) {
        const int m = m0 + mt * 16 + col;
        const float bv  = bias[m];
        const float spv = sp[m];
        const float tpv = tp[m];
#pragma unroll
        for (int r = 0; r < 4; r++) {
            float v = accs[mt][r] + bv;
            Cb[(size_t)(rbase + r) * HD + m] = f2bf(v);
            ps[r] += v * spv;
            pt[r] += v * tpv;
        }
    }
#pragma unroll
    for (int off = 1; off <= 8; off <<= 1) {
#pragma unroll
        for (int r = 0; r < 4; r++) {
            ps[r] += __shfl_xor(ps[r], off, 64);
            pt[r] += __shfl_xor(pt[r], off, 64);
        }
    }
    if (col < 4)
        src[(rbase + col) * 8 + h] = ps[col];
    else if (col < 8)
        trg[(rbase + col - 4) * 8 + h] = pt[col - 4];
}

// ---------------- K2: fused edge-scan + balanced gather attention ------------
// One WG (4 waves) per row i.
//  phase 1: wave w ballot-scans conn[i, w*1024 ..] into its LDS segment.
//  phase 1b: segments compacted into one list; padded by 3 sentinels so the
//            gather prefetch elist[k+3] needs no clamp.
//  phase 2: wave w gathers the balanced range [tot*w/4, tot*(w+1)/4): per edge
//           the wave reads the 1KB bf16 V row (lane=(h,d8), uint4 = 8 bf16)
//           + trg scalar, accumulating unnormalized acc + denominator lsum.
//  phase 3: combine 4 partials via LDS, divide once, store.
// conn==0.0f exactly marks kept edges; |e|<~6 so no max-subtraction needed.
__global__ __launch_bounds__(256) void k_rowattn(const float* __restrict__ conn,
                                                 const float* __restrict__ src,
                                                 const float* __restrict__ trg,
                                                 const unsigned short* __restrict__ d1b,
                                                 float* __restrict__ out) {
    __shared__ unsigned short seg[4][QCAP];
    __shared__ unsigned short elist[RCAP + 8];
    __shared__ int wcnt[4];
    __shared__ float cbuf[3][64][9];   // waves 1..3 deposit acc[8]+lsum
    const int w = threadIdx.x >> 6, lane = threadIdx.x & 63;
    const int i = blockIdx.x;
    const int h = lane >> 3, d8 = lane & 7;

    // ---- phase 1: scan this wave's quarter of the conn row ----
    const float* crow = conn + (size_t)i * NN + w * 1024;
    int cnt = 0;
#pragma unroll
    for (int c0 = 0; c0 < 1024; c0 += 256) {
        float4 c = *(const float4*)(crow + c0 + lane * 4);
        float cv[4] = {c.x, c.y, c.z, c.w};
#pragma unroll
        for (int q = 0; q < 4; q++) {
            bool edge = (cv[q] == 0.0f);
            unsigned long long mask = __ballot(edge);
            int pre = __popcll(mask & ((1ull << lane) - 1ull));
            int pos = cnt + pre;
            if (edge && pos < QCAP)
                seg[w][pos] = (unsigned short)(w * 1024 + c0 + lane * 4 + q);
            cnt += __popcll(mask);
        }
    }
    if (cnt > QCAP) cnt = QCAP;
    if (lane == 0) wcnt[w] = cnt;
    __syncthreads();

    // ---- phase 1b: compact into one contiguous list + sentinel pad ----
    const int c0n = wcnt[0], c1n = wcnt[1], c2n = wcnt[2], c3n = wcnt[3];
    int tot = c0n + c1n + c2n + c3n;
    if (tot > RCAP) tot = RCAP;   // (unreachable in practice)
    const int base = (w == 0) ? 0 : (w == 1) ? c0n
                   : (w == 2) ? c0n + c1n : c0n + c1n + c2n;
    for (int k = lane; k < cnt && base + k < RCAP; k += 64)
        elist[base + k] = seg[w][k];
    __syncthreads();
    if (threadIdx.x < 4)
        elist[tot + threadIdx.x] = (tot > 0) ? elist[tot - 1] : (unsigned short)0;
    __syncthreads();

    // ---- phase 2: balanced gather ----
    const float sh = src[i * 8 + h];
    const unsigned voffB = (unsigned)(h * 64 + d8 * 8) * 2u;
    const unsigned toffB = (unsigned)h << 2;
    const unsigned char* vb = (const unsigned char*)d1b;
    const unsigned char* tb = (const unsigned char*)trg;
    const int kbeg = (tot * w) >> 2;
    const int kend = (tot * (w + 1)) >> 2;

    float acc[8] = {0.f, 0.f, 0.f, 0.f, 0.f, 0.f, 0.f, 0.f};
    float lsum = 0.f;
    if (kend > kbeg) {
        unsigned j0 = elist[kbeg];
        unsigned j1 = elist[kbeg + 1];
        unsigned j2 = elist[kbeg + 2];
        float t0 = *(const float*)(tb + (j0 << 5) + toffB);
        float t1 = *(const float*)(tb + (j1 << 5) + toffB);
        uint4 U0 = *(const uint4*)(vb + (j0 << 10) + voffB);
        uint4 U1 = *(const uint4*)(vb + (j1 << 10) + voffB);
#pragma unroll 3
        for (int k = kbeg; k < kend; k++) {
            unsigned j3 = elist[k + 3];          // sentinel-padded: no clamp
            float t2 = *(const float*)(tb + (j2 << 5) + toffB);
            uint4 U2 = *(const uint4*)(vb + (j2 << 10) + voffB);
            float e = sh + t0;
            e = fmaxf(e, 0.01f * e);             // LeakyReLU
            float p = __expf(e);
            lsum += p;
            acc[0] += p * __uint_as_float(U0.x << 16);
            acc[1] += p * __uint_as_float(U0.x & 0xffff0000u);
            acc[2] += p * __uint_as_float(U0.y << 16);
            acc[3] += p * __uint_as_float(U0.y & 0xffff0000u);
            acc[4] += p * __uint_as_float(U0.z << 16);
            acc[5] += p * __uint_as_float(U0.z & 0xffff0000u);
            acc[6] += p * __uint_as_float(U0.w << 16);
            acc[7] += p * __uint_as_float(U0.w & 0xffff0000u);
            t0 = t1; t1 = t2;
            U0 = U1; U1 = U2;
            j2 = j3;
        }
    }

    // ---- phase 3: combine 4 wave-partials, normalize, store ----
    if (w > 0) {
#pragma unroll
        for (int r = 0; r < 8; r++) cbuf[w - 1][lane][r] = acc[r];
        cbuf[w - 1][lane][8] = lsum;
    }
    __syncthreads();
    if (w == 0) {
#pragma unroll
        for (int wv = 0; wv < 3; wv++) {
#pragma unroll
            for (int r = 0; r < 8; r++) acc[r] += cbuf[wv][lane][r];
            lsum += cbuf[wv][lane][8];
        }
        float inv = (lsum > 0.f) ? (1.f / lsum) : 0.f;
        float* op = out + (size_t)i * HD + h * 64 + d8 * 8;
        *(float4*)op = make_float4(acc[0] * inv, acc[1] * inv, acc[2] * inv, acc[3] * inv);
        *(float4*)(op + 4) = make_float4(acc[4] * inv, acc[5] * inv, acc[6] * inv, acc[7] * inv);
    }
}

extern "C" void kernel_launch(void* const* d_in, const int* in_sizes, int n_in,
                              void* d_out, int out_size, void* d_ws, size_t ws_size,
                              hipStream_t stream) {
    const float* data = (const float*)d_in[0];   // (4096, 512)
    const float* conn = (const float*)d_in[1];   // (4096, 4096)
    const float* W    = (const float*)d_in[2];   // (512, 512)
    const float* bias = (const float*)d_in[3];   // (512,)
    const float* sp   = (const float*)d_in[4];   // (1, 8, 64)
    const float* tp   = (const float*)d_in[5];   // (1, 8, 64)
    float* out = (float*)d_out;                  // (4096, 512) fp32

    unsigned short* d1b = (unsigned short*)d_ws;              // 2M bf16 (4 MB)
    float* src  = (float*)(d1b + (size_t)NN * HD);            // 128 KB
    float* trg  = src + NN * NH;                              // 128 KB
    // total ~4.4 MB

    k_prep<<<dim3(NH, NN / 64), 256, 0, stream>>>(data, W, bias, sp, tp, d1b, src, trg);
    k_rowattn<<<dim3(NN), 256, 0, stream>>>(conn, src, trg, d1b, out);
}

// Round 9
// 166.169 us; speedup vs baseline: 1.1151x; 1.1151x over previous
//
#include <hip/hip_runtime.h>
#include <hip/hip_bf16.h>

#define NN 4096
#define IN_DIM 512
#define NH 8
#define DD 64
#define HD 512    // NH*DD
#define QCAP 128  // per-quarter cap: Binomial(1024,.05) mean 51 sigma 7 -> +11 sigma
#define RCAP 448  // per-row cap: mean 205 sigma 14 -> +17 sigma

// Workspace: d1b 4MB + Ab 4MB + Wb 0.5MB + src/trg 0.25MB ~= 8.75 MB
// (R3 lesson: stay well under ~12 MB; R7 proved 8.75 MB works).

typedef __attribute__((ext_vector_type(8))) short short8;
typedef __attribute__((ext_vector_type(4))) float f32x4;
typedef __attribute__((ext_vector_type(2))) float f32x2;

static __device__ __forceinline__ unsigned short f2bf(float x) {
    __hip_bfloat16 h = __float2bfloat16(x);
    return *reinterpret_cast<unsigned short*>(&h);
}

// ---------------- K0: fp32 -> bf16 cast of data and W (one launch) -----------
// Cast ONCE here; R8 fused the cast into the GEMM and paid 64x-redundant
// per-fragment conversion VALU — that was a 20 us regression.
__global__ __launch_bounds__(256) void k_cast2(const float* __restrict__ inA,
                                               unsigned short* __restrict__ outA,
                                               int n4A,
                                               const float* __restrict__ inB,
                                               unsigned short* __restrict__ outB,
                                               int n4B) {
    int t = blockIdx.x * 256 + threadIdx.x;
    const float* in;
    unsigned short* out;
    if (t < n4A) {
        in = inA; out = outA;
    } else {
        t -= n4A;
        if (t >= n4B) return;
        in = inB; out = outB;
    }
    float4 v = ((const float4*)in)[t];
    ushort4 o;
    o.x = f2bf(v.x); o.y = f2bf(v.y); o.z = f2bf(v.z); o.w = f2bf(v.w);
    ((ushort4*)out)[t] = o;
}

// ---------------- K1: GEMM (bf16 MFMA) + fused src/trg projection ------------
// 64n x 64m per WG; m-tile == one head h = blockIdx.x. Fragments straight
// from global (k-major). C/D: col=lane&15, row=(lane>>4)*4+reg (m89-verified).
__global__ __launch_bounds__(256) void k_gemm_fused(const unsigned short* __restrict__ Ab,
                                                    const unsigned short* __restrict__ Wb,
                                                    const float* __restrict__ bias,
                                                    const float* __restrict__ sp,
                                                    const float* __restrict__ tp,
                                                    unsigned short* __restrict__ Cb,
                                                    float* __restrict__ src,
                                                    float* __restrict__ trg) {
    const int lane = threadIdx.x & 63;
    const int w = threadIdx.x >> 6;
    const int col = lane & 15;
    const int quad = lane >> 4;
    const int koff = quad * 8;
    const int h = blockIdx.x;
    const int m0 = h * 64;
    const int n0 = blockIdx.y * 64;

    const short8* ap  = (const short8*)(Ab + (size_t)(n0 + w * 16 + col) * IN_DIM + koff);
    const short8* bp0 = (const short8*)(Wb + (size_t)(m0 +  0 + col) * IN_DIM + koff);
    const short8* bp1 = (const short8*)(Wb + (size_t)(m0 + 16 + col) * IN_DIM + koff);
    const short8* bp2 = (const short8*)(Wb + (size_t)(m0 + 32 + col) * IN_DIM + koff);
    const short8* bp3 = (const short8*)(Wb + (size_t)(m0 + 48 + col) * IN_DIM + koff);

    f32x4 acc0 = {0.f, 0.f, 0.f, 0.f}, acc1 = acc0, acc2 = acc0, acc3 = acc0;

#pragma unroll 4
    for (int ks = 0; ks < 16; ks++) {
        short8 a  = ap[ks * 4];
        short8 b0 = bp0[ks * 4];
        short8 b1 = bp1[ks * 4];
        short8 b2 = bp2[ks * 4];
        short8 b3 = bp3[ks * 4];
        acc0 = __builtin_amdgcn_mfma_f32_16x16x32_bf16(a, b0, acc0, 0, 0, 0);
        acc1 = __builtin_amdgcn_mfma_f32_16x16x32_bf16(a, b1, acc1, 0, 0, 0);
        acc2 = __builtin_amdgcn_mfma_f32_16x16x32_bf16(a, b2, acc2, 0, 0, 0);
        acc3 = __builtin_amdgcn_mfma_f32_16x16x32_bf16(a, b3, acc3, 0, 0, 0);
    }

    const int rbase = n0 + w * 16 + quad * 4;
    f32x4 accs[4] = {acc0, acc1, acc2, acc3};
    float ps[4] = {0.f, 0.f, 0.f, 0.f};
    float pt[4] = {0.f, 0.f, 0.f, 0.f};
#pragma unroll
    for (int mt = 0; mt < 4; mt++) {
        const int m = m0 + mt * 16 + col;
        const float bv  = bias[m];
        const float spv = sp[m];
        const float tpv = tp[m];
#pragma unroll
        for (int r = 0; r < 4; r++) {
            float v = accs[mt][r] + bv;
            Cb[(size_t)(rbase + r) * HD + m] = f2bf(v);
            ps[r] += v * spv;
            pt[r] += v * tpv;
        }
    }
#pragma unroll
    for (int off = 1; off <= 8; off <<= 1) {
#pragma unroll
        for (int r = 0; r < 4; r++) {
            ps[r] += __shfl_xor(ps[r], off, 64);
            pt[r] += __shfl_xor(pt[r], off, 64);
        }
    }
    if (col < 4)
        src[(rbase + col) * 8 + h] = ps[col];
    else if (col < 8)
        trg[(rbase + col - 4) * 8 + h] = pt[col - 4];
}

// ---------------- K2: fused edge-scan + balanced gather attention ------------
// One WG (4 waves) per row i. Phase 1: per-wave ballot-scan of a conn quarter;
// 1b: compact to one LDS list + 3 sentinels (prefetch needs no clamp);
// 2: balanced per-wave gather, f32x2 packed accumulate (v_pk_fma_f32) of the
//    1KB bf16 V row (lane=(h,d8), uint4 = 8 bf16) + inline denominator;
// 3: LDS combine, divide once, store.
// conn==0.0f exactly marks kept edges; |e|<~6 so no max-subtraction needed.
__global__ __launch_bounds__(256) void k_rowattn(const float* __restrict__ conn,
                                                 const float* __restrict__ src,
                                                 const float* __restrict__ trg,
                                                 const unsigned short* __restrict__ d1b,
                                                 float* __restrict__ out) {
    __shared__ unsigned short seg[4][QCAP];
    __shared__ unsigned short elist[RCAP + 8];
    __shared__ int wcnt[4];
    __shared__ float cbuf[3][64][9];   // waves 1..3 deposit acc[8]+lsum
    const int w = threadIdx.x >> 6, lane = threadIdx.x & 63;
    const int i = blockIdx.x;
    const int h = lane >> 3, d8 = lane & 7;

    // ---- phase 1: scan this wave's quarter of the conn row ----
    const float* crow = conn + (size_t)i * NN + w * 1024;
    int cnt = 0;
#pragma unroll
    for (int c0 = 0; c0 < 1024; c0 += 256) {
        float4 c = *(const float4*)(crow + c0 + lane * 4);
        float cv[4] = {c.x, c.y, c.z, c.w};
#pragma unroll
        for (int q = 0; q < 4; q++) {
            bool edge = (cv[q] == 0.0f);
            unsigned long long mask = __ballot(edge);
            int pre = __popcll(mask & ((1ull << lane) - 1ull));
            int pos = cnt + pre;
            if (edge && pos < QCAP)
                seg[w][pos] = (unsigned short)(w * 1024 + c0 + lane * 4 + q);
            cnt += __popcll(mask);
        }
    }
    if (cnt > QCAP) cnt = QCAP;
    if (lane == 0) wcnt[w] = cnt;
    __syncthreads();

    // ---- phase 1b: compact into one contiguous list + sentinel pad ----
    const int c0n = wcnt[0], c1n = wcnt[1], c2n = wcnt[2], c3n = wcnt[3];
    int tot = c0n + c1n + c2n + c3n;
    if (tot > RCAP) tot = RCAP;   // (unreachable in practice)
    const int base = (w == 0) ? 0 : (w == 1) ? c0n
                   : (w == 2) ? c0n + c1n : c0n + c1n + c2n;
    for (int k = lane; k < cnt && base + k < RCAP; k += 64)
        elist[base + k] = seg[w][k];
    __syncthreads();
    if (threadIdx.x < 4)
        elist[tot + threadIdx.x] = (tot > 0) ? elist[tot - 1] : (unsigned short)0;
    __syncthreads();

    // ---- phase 2: balanced gather, packed accumulate ----
    const float sh = src[i * 8 + h];
    const unsigned voffB = (unsigned)(h * 64 + d8 * 8) * 2u;
    const unsigned toffB = (unsigned)h << 2;
    const unsigned char* vb = (const unsigned char*)d1b;
    const unsigned char* tb = (const unsigned char*)trg;
    const int kbeg = (tot * w) >> 2;
    const int kend = (tot * (w + 1)) >> 2;

    f32x2 a01 = {0.f, 0.f}, a23 = a01, a45 = a01, a67 = a01;
    float lsum = 0.f;
    if (kend > kbeg) {
        unsigned j0 = elist[kbeg];
        unsigned j1 = elist[kbeg + 1];
        unsigned j2 = elist[kbeg + 2];
        float t0 = *(const float*)(tb + (j0 << 5) + toffB);
        float t1 = *(const float*)(tb + (j1 << 5) + toffB);
        uint4 U0 = *(const uint4*)(vb + (j0 << 10) + voffB);
        uint4 U1 = *(const uint4*)(vb + (j1 << 10) + voffB);
#pragma unroll 3
        for (int k = kbeg; k < kend; k++) {
            unsigned j3 = elist[k + 3];          // sentinel-padded: no clamp
            float t2 = *(const float*)(tb + (j2 << 5) + toffB);
            uint4 U2 = *(const uint4*)(vb + (j2 << 10) + voffB);
            float e = sh + t0;
            e = fmaxf(e, 0.01f * e);             // LeakyReLU
            float p = __expf(e);
            lsum += p;
            f32x2 p2 = {p, p};
            f32x2 v01 = {__uint_as_float(U0.x << 16), __uint_as_float(U0.x & 0xffff0000u)};
            f32x2 v23 = {__uint_as_float(U0.y << 16), __uint_as_float(U0.y & 0xffff0000u)};
            f32x2 v45 = {__uint_as_float(U0.z << 16), __uint_as_float(U0.z & 0xffff0000u)};
            f32x2 v67 = {__uint_as_float(U0.w << 16), __uint_as_float(U0.w & 0xffff0000u)};
            a01 += p2 * v01;                     // v_pk_fma_f32
            a23 += p2 * v23;
            a45 += p2 * v45;
            a67 += p2 * v67;
            t0 = t1; t1 = t2;
            U0 = U1; U1 = U2;
            j2 = j3;
        }
    }

    // ---- phase 3: combine 4 wave-partials, normalize, store ----
    float acc[8] = {a01.x, a01.y, a23.x, a23.y, a45.x, a45.y, a67.x, a67.y};
    if (w > 0) {
#pragma unroll
        for (int r = 0; r < 8; r++) cbuf[w - 1][lane][r] = acc[r];
        cbuf[w - 1][lane][8] = lsum;
    }
    __syncthreads();
    if (w == 0) {
#pragma unroll
        for (int wv = 0; wv < 3; wv++) {
#pragma unroll
            for (int r = 0; r < 8; r++) acc[r] += cbuf[wv][lane][r];
            lsum += cbuf[wv][lane][8];
        }
        float inv = (lsum > 0.f) ? (1.f / lsum) : 0.f;
        float* op = out + (size_t)i * HD + h * 64 + d8 * 8;
        *(float4*)op = make_float4(acc[0] * inv, acc[1] * inv, acc[2] * inv, acc[3] * inv);
        *(float4*)(op + 4) = make_float4(acc[4] * inv, acc[5] * inv, acc[6] * inv, acc[7] * inv);
    }
}

extern "C" void kernel_launch(void* const* d_in, const int* in_sizes, int n_in,
                              void* d_out, int out_size, void* d_ws, size_t ws_size,
                              hipStream_t stream) {
    const float* data = (const float*)d_in[0];   // (4096, 512)
    const float* conn = (const float*)d_in[1];   // (4096, 4096)
    const float* W    = (const float*)d_in[2];   // (512, 512)
    const float* bias = (const float*)d_in[3];   // (512,)
    const float* sp   = (const float*)d_in[4];   // (1, 8, 64)
    const float* tp   = (const float*)d_in[5];   // (1, 8, 64)
    float* out = (float*)d_out;                  // (4096, 512) fp32

    unsigned short* d1b = (unsigned short*)d_ws;              // 2M bf16 (4 MB)
    unsigned short* Ab  = d1b + (size_t)NN * HD;              // 2M bf16 (4 MB)
    unsigned short* Wb  = Ab + (size_t)NN * IN_DIM;           // 256K bf16 (512 KB)
    float* src  = (float*)(Wb + (size_t)HD * IN_DIM);         // 128 KB
    float* trg  = src + NN * NH;                              // 128 KB
    // total ~8.75 MB

    const int n4A = NN * IN_DIM / 4;   // 524288
    const int n4B = HD * IN_DIM / 4;   // 65536
    k_cast2<<<dim3((n4A + n4B + 255) / 256), 256, 0, stream>>>(data, Ab, n4A, W, Wb, n4B);
    k_gemm_fused<<<dim3(NH, NN / 64), 256, 0, stream>>>(Ab, Wb, bias, sp, tp, d1b, src, trg);
    k_rowattn<<<dim3(NN), 256, 0, stream>>>(conn, src, trg, d1b, out);
}